// Round 11
// baseline (176.786 us; speedup 1.0000x reference)
//
#include <hip/hip_runtime.h>

#define IMG 224
#define HW (IMG * IMG)
#define TILE 32
#define PAD 4
#define REG (TILE + 2 * PAD)   // 40 staged rows/cols
#define RSA 41                 // A-table row stride in float2 (odd -> bank walk)
#define TABA (REG * RSA)       // 1640 float2 per image (ch0,ch1)
#define RSB 44                 // B-table row stride in floats (16B-aligned writes)
#define TABB (REG * RSB)       // 1760 floats per image (ch2)
#define BUFF 10080             // floats per tile buffer: 2*1640*2 + 2*1760
#define TPT 7                  // tiles per block (one 32-wide column of one n)
#define NBLK 448               // 3136 / 7 ; 448 % 8 == 0 -> bijective swizzle
#define NXCD 8

typedef float vf2 __attribute__((ext_vector_type(2)));

struct U3 { float4 a, b, c; };

__device__ __forceinline__ U3 load3(const float* __restrict__ src, int gi) {
    U3 u;
    if (gi >= 0 && gi <= HW - 4) {
        u.a = *(const float4*)(src + gi);
        u.b = *(const float4*)(src + HW + gi);
        u.c = *(const float4*)(src + 2 * HW + gi);
    } else {                        // flat-clamp edge rows (rare)
#pragma unroll
        for (int i = 0; i < 4; ++i) {
            int g = min(max(gi + i, 0), HW - 1);
            ((float*)&u.a)[i] = src[g];
            ((float*)&u.b)[i] = src[HW + g];
            ((float*)&u.c)[i] = src[2 * HW + g];
        }
    }
    return u;
}

__device__ __forceinline__ void writeU(float* __restrict__ base, int img,
                                       int r, int s, const U3& u) {
    float2* dA = (float2*)base + img * TABA + r * RSA + 4 * s;
    dA[0] = make_float2(u.a.x, u.b.x);
    dA[1] = make_float2(u.a.y, u.b.y);
    dA[2] = make_float2(u.a.z, u.b.z);
    dA[3] = make_float2(u.a.w, u.b.w);
    *(float4*)(base + 6560 + img * TABB + r * RSB + 4 * s) = u.c;
}

__device__ __forceinline__ void compute_px(
    const float* __restrict__ Bf, int xlo, int ylo,
    float xf, int p, int yfb,
    vf2 c0v, vf2 c1v, vf2 m1v, vf2 m2v,
    const float* __restrict__ i1n, const float* __restrict__ i2n,
    float* __restrict__ on)
{
    const float2* TA = (const float2*)Bf;
    const float*  TB = Bf + 6560;
    float acc0[2], acc1[2], acc2[2];

#pragma unroll
    for (int i = 0; i < 2; ++i) {
        const float yf  = (float)(yfb + i);
        const float cc0 = c0v[i], cc1 = c1v[i];
        const float m1i = m1v[i], m2i = m2v[i];
        float r0c, r1c, r2c;

        {   // +C on im1
            float px = xf + cc0, py = yf + cc1;
            float fx = floorf(px), cx = ceilf(px);
            float fy = floorf(py), cy = ceilf(py);
            float wfx = 1.0f - (px - fx), wcx = 1.0f - (cx - px);
            float wfy = 1.0f - (py - fy), wcy = 1.0f - (cy - py);
            float w0 = wfx * wfy, w1 = wcx * wfy;
            float w2 = wfx * wcy, w3 = wcx * wcy;
            int gx0 = (int)fx, gy0 = (int)fy;
            int dx = (int)cx - gx0, dy = (int)cy - gy0;
            int q0 = gx0 - xlo, r0 = gy0 - ylo;
            int in = (q0 >= 0) & (q0 + dx <= REG - 1) &
                     (r0 >= 0) & (r0 + dy <= REG - 1);
            if (__all(in)) {
                int oA = r0 * RSA + q0, oB = r0 * RSB + q0;
                float2 A0 = TA[oA],            A1 = TA[oA + dx];
                float2 A2 = TA[oA + dy * RSA], A3 = TA[oA + dx + dy * RSA];
                float  b0 = TB[oB],            b1 = TB[oB + dx];
                float  b2 = TB[oB + dy * RSB], b3 = TB[oB + dx + dy * RSB];
                r0c = m1i * (w0 * A0.x + w1 * A1.x + w2 * A2.x + w3 * A3.x);
                r1c = m1i * (w0 * A0.y + w1 * A1.y + w2 * A2.y + w3 * A3.y);
                r2c = m1i * (w0 * b0   + w1 * b1   + w2 * b2   + w3 * b3);
            } else {   // rare: beyond PAD -> global clamped gather
                int i0 = min(max(gx0      + IMG * gy0,        0), HW - 1);
                int i1 = min(max(gx0 + dx + IMG * gy0,        0), HW - 1);
                int i2 = min(max(gx0      + IMG * (gy0 + dy), 0), HW - 1);
                int i3 = min(max(gx0 + dx + IMG * (gy0 + dy), 0), HW - 1);
                r0c = m1i * (w0 * i1n[i0] + w1 * i1n[i1] +
                             w2 * i1n[i2] + w3 * i1n[i3]);
                r1c = m1i * (w0 * i1n[HW + i0] + w1 * i1n[HW + i1] +
                             w2 * i1n[HW + i2] + w3 * i1n[HW + i3]);
                r2c = m1i * (w0 * i1n[2 * HW + i0] + w1 * i1n[2 * HW + i1] +
                             w2 * i1n[2 * HW + i2] + w3 * i1n[2 * HW + i3]);
            }
        }
        {   // -C on im2
            float px = xf - cc0, py = yf - cc1;
            float fx = floorf(px), cx = ceilf(px);
            float fy = floorf(py), cy = ceilf(py);
            float wfx = 1.0f - (px - fx), wcx = 1.0f - (cx - px);
            float wfy = 1.0f - (py - fy), wcy = 1.0f - (cy - py);
            float w0 = wfx * wfy, w1 = wcx * wfy;
            float w2 = wfx * wcy, w3 = wcx * wcy;
            int gx0 = (int)fx, gy0 = (int)fy;
            int dx = (int)cx - gx0, dy = (int)cy - gy0;
            int q0 = gx0 - xlo, r0 = gy0 - ylo;
            int in = (q0 >= 0) & (q0 + dx <= REG - 1) &
                     (r0 >= 0) & (r0 + dy <= REG - 1);
            if (__all(in)) {
                const float2* TA2 = TA + TABA;
                const float*  TB2 = TB + TABB;
                int oA = r0 * RSA + q0, oB = r0 * RSB + q0;
                float2 A0 = TA2[oA],            A1 = TA2[oA + dx];
                float2 A2 = TA2[oA + dy * RSA], A3 = TA2[oA + dx + dy * RSA];
                float  b0 = TB2[oB],            b1 = TB2[oB + dx];
                float  b2 = TB2[oB + dy * RSB], b3 = TB2[oB + dx + dy * RSB];
                r0c += m2i * (w0 * A0.x + w1 * A1.x + w2 * A2.x + w3 * A3.x);
                r1c += m2i * (w0 * A0.y + w1 * A1.y + w2 * A2.y + w3 * A3.y);
                r2c += m2i * (w0 * b0   + w1 * b1   + w2 * b2   + w3 * b3);
            } else {
                int i0 = min(max(gx0      + IMG * gy0,        0), HW - 1);
                int i1 = min(max(gx0 + dx + IMG * gy0,        0), HW - 1);
                int i2 = min(max(gx0      + IMG * (gy0 + dy), 0), HW - 1);
                int i3 = min(max(gx0 + dx + IMG * (gy0 + dy), 0), HW - 1);
                r0c += m2i * (w0 * i2n[i0] + w1 * i2n[i1] +
                              w2 * i2n[i2] + w3 * i2n[i3]);
                r1c += m2i * (w0 * i2n[HW + i0] + w1 * i2n[HW + i1] +
                              w2 * i2n[HW + i2] + w3 * i2n[HW + i3]);
                r2c += m2i * (w0 * i2n[2 * HW + i0] + w1 * i2n[2 * HW + i1] +
                              w2 * i2n[2 * HW + i2] + w3 * i2n[2 * HW + i3]);
            }
        }
        acc0[i] = r0c; acc1[i] = r1c; acc2[i] = r2c;
    }

    vf2 o0 = {acc0[0], acc0[1]};
    vf2 o1 = {acc1[0], acc1[1]};
    vf2 o2 = {acc2[0], acc2[1]};
    __builtin_nontemporal_store(o0, (vf2*)(on + p));
    __builtin_nontemporal_store(o1, (vf2*)(on + HW + p));
    __builtin_nontemporal_store(o2, (vf2*)(on + 2 * HW + p));
}

__global__ __launch_bounds__(512, 4) void vm_kernel(
    const float* __restrict__ im1, const float* __restrict__ im2,
    const float* __restrict__ C, const float* __restrict__ M1,
    const float* __restrict__ M2, float* __restrict__ out)
{
    // double-buffered pair-layout: 2 x 40,320 B = 80,640 B -> 2 blocks/CU
    __shared__ __align__(16) float lds[2 * BUFF];

    // XCD swizzle: 56 blocks/XCD = 8 whole n's (verified R7: FETCH 150->63MB)
    const int bid  = blockIdx.x;
    const int b    = (bid & (NXCD - 1)) * (NBLK / NXCD) + (bid >> 3);
    const int n    = b / 7;
    const int xcol = b - n * 7;

    const int x0  = xcol * TILE;
    const int t   = threadIdx.x;
    const int xlo = x0 - PAD;

    const float* i1n = im1 + (size_t)n * 3 * HW;
    const float* i2n = im2 + (size_t)n * 3 * HW;
    const float* Cn  = C  + (size_t)n * 2 * HW;
    const float* M1n = M1 + (size_t)n * HW;
    const float* M2n = M2 + (size_t)n * HW;
    float*       on  = out + (size_t)n * 3 * HW;

    // pixel mapping: 512 threads x 2 px
    const int tx    = t >> 4;              // 0..31 (slow coord)
    const int ty0   = (t & 15) * 2;        // 0,2,..,30 (fast coord base)
    const int pbase = (x0 + tx) * IMG + ty0;
    const float xf  = (float)(x0 + tx);

    // staging units: 800 units (2 img x 400) over 512 threads
    const bool a1 = (t < 400);
    const bool a2 = (t >= 112);
    const int e1 = t,        r1 = e1 / 10, s1 = e1 - 10 * r1;
    const int e2 = t - 112,  r2 = e2 / 10, s2 = e2 - 10 * r2;

    // ---- prologue: stage tile 0 (the only full-latency stall, paid once)
    {
        int gb = xlo + IMG * (-PAD);
        U3 u1, u2;
        if (a1) u1 = load3(i1n, gb + IMG * r1 + 4 * s1);
        if (a2) u2 = load3(i2n, gb + IMG * r2 + 4 * s2);
        if (a1) writeU(lds, 0, r1, s1, u1);
        if (a2) writeU(lds, 1, r2, s2, u2);
    }
    vf2 c0c = __builtin_nontemporal_load((const vf2*)(Cn + pbase));
    vf2 c1c = __builtin_nontemporal_load((const vf2*)(Cn + HW + pbase));
    vf2 m1c = __builtin_nontemporal_load((const vf2*)(M1n + pbase));
    vf2 m2c = __builtin_nontemporal_load((const vf2*)(M2n + pbase));
    __syncthreads();

#pragma unroll 1
    for (int k = 0; k < TPT; ++k) {
        const int ylo = k * TILE - PAD;
        float* Bc = lds + (k & 1) * BUFF;
        float* Bn = lds + ((k + 1) & 1) * BUFF;

        // issue next tile's loads EARLY (latency hides under compute below)
        U3 v1, v2;
        vf2 c0n, c1n, m1n, m2n;
        if (k < TPT - 1) {
            int gbn = xlo + IMG * (ylo + TILE);
            if (a1) v1 = load3(i1n, gbn + IMG * r1 + 4 * s1);
            if (a2) v2 = load3(i2n, gbn + IMG * r2 + 4 * s2);
            int pn = pbase + (k + 1) * TILE;
            c0n = __builtin_nontemporal_load((const vf2*)(Cn + pn));
            c1n = __builtin_nontemporal_load((const vf2*)(Cn + HW + pn));
            m1n = __builtin_nontemporal_load((const vf2*)(M1n + pn));
            m2n = __builtin_nontemporal_load((const vf2*)(M2n + pn));
        }

        // compute tile k from buf[k&1] (next-tile loads in flight)
        compute_px(Bc, xlo, ylo, xf, pbase + k * TILE, k * TILE + ty0,
                   c0c, c1c, m1c, m2c, i1n, i2n, on);

        // write next tile LATE (loads landed during compute -> no stall)
        if (k < TPT - 1) {
            if (a1) writeU(Bn, 0, r1, s1, v1);
            if (a2) writeU(Bn, 1, r2, s2, v2);
            c0c = c0n; c1c = c1n; m1c = m1n; m2c = m2n;
        }
        __syncthreads();   // writes visible; no vmem loads in flight here
    }
}

extern "C" void kernel_launch(void* const* d_in, const int* in_sizes, int n_in,
                              void* d_out, int out_size, void* d_ws, size_t ws_size,
                              hipStream_t stream) {
    const float* im1 = (const float*)d_in[0];
    const float* im2 = (const float*)d_in[1];
    const float* C   = (const float*)d_in[2];
    const float* M1  = (const float*)d_in[3];
    const float* M2  = (const float*)d_in[4];
    float* out = (float*)d_out;
    vm_kernel<<<dim3(NBLK), 512, 0, stream>>>(im1, im2, C, M1, M2, out);
}